// Round 36
// baseline (176.655 us; speedup 1.0000x reference)
//
#include <hip/hip_runtime.h>
#include <math.h>

static constexpr int S_LEN  = 4096;
static constexpr int DMODEL = 768;
static constexpr int NHEAD  = 12;
static constexpr int HDIM   = 64;

typedef __attribute__((ext_vector_type(8))) short   bf16x8;
typedef __attribute__((ext_vector_type(4))) float   f32x4;
typedef __attribute__((ext_vector_type(8))) unsigned short us8;

__device__ __forceinline__ unsigned short f2b(float f) {
  union { float f; unsigned int u; } v; v.f = f;
  unsigned int u = v.u;
  return (unsigned short)((u + 0x7fffu + ((u >> 16) & 1u)) >> 16);  // RNE
}

// HW bf16 convert (RNE)
__device__ __forceinline__ unsigned short f2b_fast(float f) {
  unsigned int u;
  asm("v_cvt_pk_bf16_f32 %0, %1, %2" : "=v"(u) : "v"(f), "v"(0.f));
  return (unsigned short)u;
}
__device__ __forceinline__ unsigned int cvt_pk(float lo, float hi) {
  unsigned int u;
  asm("v_cvt_pk_bf16_f32 %0, %1, %2" : "=v"(u) : "v"(lo), "v"(hi));
  return u;
}

// ---------------------------------------------------------------------------
// fp32 -> bf16 bulk convert
// ---------------------------------------------------------------------------
__global__ __launch_bounds__(256)
void cvt_f2b_kern(const float* __restrict__ in, unsigned short* __restrict__ out, int n) {
  int i = (blockIdx.x * blockDim.x + threadIdx.x) * 8;
  if (i >= n) return;
  float4 a = *(const float4*)(in + i);
  float4 b = *(const float4*)(in + i + 4);
  ushort4 o0; o0.x = f2b(a.x); o0.y = f2b(a.y); o0.z = f2b(a.z); o0.w = f2b(a.w);
  ushort4 o1; o1.x = f2b(b.x); o1.y = f2b(b.y); o1.z = f2b(b.z); o1.w = f2b(b.w);
  *(ushort4*)(out + i)     = o0;
  *(ushort4*)(out + i + 4) = o1;
}

// 4 weight matrices in one launch (blockIdx.y selects the matrix)
__global__ __launch_bounds__(256)
void cvt_f2b4_kern(const float* __restrict__ s0, const float* __restrict__ s1,
                   const float* __restrict__ s2, const float* __restrict__ s3,
                   unsigned short* __restrict__ d0, unsigned short* __restrict__ d1,
                   unsigned short* __restrict__ d2, unsigned short* __restrict__ d3,
                   int n) {
  const float* s; unsigned short* d;
  switch (blockIdx.y) {
    case 0: s = s0; d = d0; break;
    case 1: s = s1; d = d1; break;
    case 2: s = s2; d = d2; break;
    default: s = s3; d = d3; break;
  }
  int i = (blockIdx.x * blockDim.x + threadIdx.x) * 8;
  if (i >= n) return;
  float4 a = *(const float4*)(s + i);
  float4 b = *(const float4*)(s + i + 4);
  ushort4 o0; o0.x = f2b(a.x); o0.y = f2b(a.y); o0.z = f2b(a.z); o0.w = f2b(a.w);
  ushort4 o1; o1.x = f2b(b.x); o1.y = f2b(b.y); o1.z = f2b(b.z); o1.w = f2b(b.w);
  *(ushort4*)(d + i)     = o0;
  *(ushort4*)(d + i + 4) = o1;
}

// ---------------------------------------------------------------------------
// bf16 transpose: in [S][D] -> out [D][S], 64x64 tiles via LDS.
// ---------------------------------------------------------------------------
__global__ __launch_bounds__(256)
void transpose_bf16(const unsigned short* __restrict__ in, unsigned short* __restrict__ out) {
  __shared__ __align__(16) unsigned short Ts[64][72];
  const int d0 = blockIdx.x * 64, s0 = blockIdx.y * 64;
  const int r = threadIdx.x >> 2, q = threadIdx.x & 3;
#pragma unroll
  for (int hh = 0; hh < 2; ++hh) {
    const int c8 = q + hh * 4;
    us8 v = *(const us8*)(in + (size_t)(s0 + r) * DMODEL + d0 + c8 * 8);
    *(us8*)(&Ts[r][c8 * 8]) = v;
  }
  __syncthreads();
#pragma unroll
  for (int hh = 0; hh < 2; ++hh) {
    const int sq = q + hh * 4;
    __align__(16) unsigned short tmp[8];
#pragma unroll
    for (int j = 0; j < 8; ++j) tmp[j] = Ts[sq * 8 + j][r];
    *(us8*)(out + (size_t)(d0 + r) * S_LEN + s0 + sq * 8) = *(us8*)tmp;
  }
}

// ---------------------------------------------------------------------------
// LDS-staged GEMM body (unchanged from R30/R31 measured build).
// ---------------------------------------------------------------------------
template<int OUT_MODE>
__device__ __forceinline__
void gemm_body(const unsigned short* __restrict__ A, const unsigned short* __restrict__ B,
               const float* __restrict__ bias, void* __restrict__ Cout,
               int M, int N, int K, float scale, int bx, int by,
               unsigned short* As, unsigned short* Bs) {
  const int l  = threadIdx.x & 63;
  const int w  = threadIdx.x >> 6;
  const int wm = (w >> 1) * 32, wn = (w & 1) * 32;
  const int m0 = by * 64;
  const int n0 = bx * 64;
  const int lr = l & 15, lg = l >> 4;
  const int sr = threadIdx.x >> 2, sq = threadIdx.x & 3;

  f32x4 acc[2][2] = {};
  us8 areg[2], breg[2];

#pragma unroll
  for (int p = 0; p < 2; ++p) {
    const int c = sq * 2 + p;
    areg[p] = *(const us8*)(A + (size_t)(m0 + sr) * K + c * 8);
    breg[p] = *(const us8*)(B + (size_t)(n0 + sr) * K + c * 8);
  }
#pragma unroll
  for (int p = 0; p < 2; ++p) {
    const int c = sq * 2 + p;
    const int slot = ((c ^ (sr & 7)) * 8);
    *(us8*)(&As[sr * 64 + slot]) = areg[p];
    *(us8*)(&Bs[sr * 64 + slot]) = breg[p];
  }
  __syncthreads();

  const int nsteps = K / 64;  // 12
  for (int t = 0; t < nsteps; ++t) {
    const bool more = (t + 1 < nsteps);
    if (more) {
      const int kn = (t + 1) * 64;
#pragma unroll
      for (int p = 0; p < 2; ++p) {
        const int c = sq * 2 + p;
        areg[p] = *(const us8*)(A + (size_t)(m0 + sr) * K + kn + c * 8);
        breg[p] = *(const us8*)(B + (size_t)(n0 + sr) * K + kn + c * 8);
      }
    }
#pragma unroll
    for (int kc = 0; kc < 2; ++kc) {
      const int cr = kc * 4 + lg;
      bf16x8 af[2], bfr[2];
#pragma unroll
      for (int mi = 0; mi < 2; ++mi) {
        const int row = wm + mi * 16 + lr;
        af[mi] = *(const bf16x8*)(&As[row * 64 + ((cr ^ (row & 7)) * 8)]);
      }
#pragma unroll
      for (int ni = 0; ni < 2; ++ni) {
        const int row = wn + ni * 16 + lr;
        bfr[ni] = *(const bf16x8*)(&Bs[row * 64 + ((cr ^ (row & 7)) * 8)]);
      }
#pragma unroll
      for (int mi = 0; mi < 2; ++mi)
#pragma unroll
        for (int ni = 0; ni < 2; ++ni)
          acc[mi][ni] = __builtin_amdgcn_mfma_f32_16x16x32_bf16(af[mi], bfr[ni], acc[mi][ni], 0, 0, 0);
    }
    __syncthreads();
    if (more) {
#pragma unroll
      for (int p = 0; p < 2; ++p) {
        const int c = sq * 2 + p;
        const int slot = ((c ^ (sr & 7)) * 8);
        *(us8*)(&As[sr * 64 + slot]) = areg[p];
        *(us8*)(&Bs[sr * 64 + slot]) = breg[p];
      }
      __syncthreads();
    }
  }

  const int orow = (l >> 4) * 4;
#pragma unroll
  for (int mi = 0; mi < 2; ++mi)
#pragma unroll
    for (int ni = 0; ni < 2; ++ni) {
      const int col = n0 + wn + ni * 16 + lr;
      float bb = (OUT_MODE == 1) ? bias[col] : 0.f;
#pragma unroll
      for (int r = 0; r < 4; ++r) {
        const int row = m0 + wm + mi * 16 + orow + r;
        float v = acc[mi][ni][r] * scale;
        if (OUT_MODE == 0)
          ((unsigned short*)Cout)[(size_t)row * N + col] = f2b(v);
        else
          ((float*)Cout)[(size_t)row * N + col] = v + bb;
      }
    }
}

// Fused QKV projection. Q scale = 0.125 * log2(e): softmax runs in exp2 domain.
__global__ __launch_bounds__(256)
void gemm_qkv_lds(const unsigned short* __restrict__ X,
                  const unsigned short* __restrict__ Wq, const unsigned short* __restrict__ Wk,
                  const unsigned short* __restrict__ Wv,
                  unsigned short* __restrict__ Qh, unsigned short* __restrict__ Kh,
                  unsigned short* __restrict__ Vh) {
  __shared__ __align__(16) unsigned short As[64 * 64];
  __shared__ __align__(16) unsigned short Bs[64 * 64];
  const unsigned short* B; unsigned short* C; float scale;
  switch (blockIdx.z) {
    case 0:  B = Wq; C = Qh; scale = 0.125f * 1.4426950408889634f; break;
    case 1:  B = Wk; C = Kh; scale = 1.0f;   break;
    default: B = Wv; C = Vh; scale = 1.0f;   break;
  }
  gemm_body<0>(X, B, nullptr, C, S_LEN, DMODEL, DMODEL, scale,
               blockIdx.x, blockIdx.y, As, Bs);
}

// Single GEMM (final projection, fp32 out + bias)
__global__ __launch_bounds__(256)
void gemm_lds_f32(const unsigned short* __restrict__ A, const unsigned short* __restrict__ B,
                  const float* __restrict__ bias, float* __restrict__ C) {
  __shared__ __align__(16) unsigned short As[64 * 64];
  __shared__ __align__(16) unsigned short Bs[64 * 64];
  gemm_body<1>(A, B, bias, C, S_LEN, DMODEL, DMODEL, 1.0f,
               blockIdx.x, blockIdx.y, As, Bs);
}

// ---------------------------------------------------------------------------
// Flash-style causal attention. R32: swapped QK^T (mfma(K,Q)) -> each lane
// owns ONE q row (q = w*16+lr) with 32 lane-local P values. Softmax is
// lane-local + 2 shfl_xor; P->PV A-frag built IN REGISTERS via 16 cvt_pk +
// 2-stage shfl butterfly (no Ps LDS round-trip). LDS 32KB -> 5 blocks/CU.
// o_acc layout unchanged (rows lg*4+r); rescale/epilogue read row values
// via __shfl(x, lg*4+r).
// ---------------------------------------------------------------------------
__global__ __launch_bounds__(256, 5)
void attn_fwd_mfma(const unsigned short* __restrict__ Q, const unsigned short* __restrict__ K,
                   const unsigned short* __restrict__ Vt, unsigned short* __restrict__ O) {
  __shared__ __align__(16) unsigned short Ks[2][64 * 64];
  __shared__ __align__(16) unsigned short Vs[2][64 * 64];

  const int item = blockIdx.x;
  int s;
  if (item < 256)      s = item;
  else if (item < 512) s = 767 - item;
  else                 s = item;
  const int qt = 63 - s / NHEAD;
  const int h  = s % NHEAD;
  const int q0 = qt * 64;
  const int tid = threadIdx.x;
  const int w = tid >> 6, l = tid & 63;
  const int lr = l & 15, lg = l >> 4;
  const int sr = tid >> 2, sq = tid & 3;
  const bool hiP = (lg >= 2);      // lg bit1
  const bool hiQ = (lg & 1) != 0;  // lg bit0

  bf16x8 qf[2];
#pragma unroll
  for (int kc = 0; kc < 2; ++kc)
    qf[kc] = *(const bf16x8*)(Q + (size_t)(q0 + w * 16 + lr) * DMODEL + h * HDIM + kc * 32 + lg * 8);

  f32x4 o_acc[4] = {};
  float m_i = -1e30f, l_i = 0.f;
  const int qg = q0 + w * 16 + lr;   // this lane's softmax row

  const int nt2    = (qt + 2) >> 1;
  const int ntFull = (64 * qt >= 127) ? ((64 * qt - 127) / 128 + 1) : 0;

  us8 kreg[2][2], vreg[2][2];

#pragma unroll
  for (int hh = 0; hh < 2; ++hh)
#pragma unroll
    for (int p = 0; p < 2; ++p) {
      const int qw = sq * 2 + p;
      kreg[hh][p] = *(const us8*)(K  + (size_t)(hh * 64 + sr) * DMODEL + h * HDIM + qw * 8);
      vreg[hh][p] = *(const us8*)(Vt + (size_t)(h * HDIM + sr) * S_LEN + hh * 64 + qw * 8);
    }
#pragma unroll
  for (int hh = 0; hh < 2; ++hh)
#pragma unroll
    for (int p = 0; p < 2; ++p) {
      const int qw = sq * 2 + p;
      const int sw = (qw * 8) ^ ((sr & 7) * 8);
      *(us8*)(&Ks[hh][sr * 64 + sw]) = kreg[hh][p];
      *(us8*)(&Vs[hh][sr * 64 + sw]) = vreg[hh][p];
    }
  __syncthreads();

  for (int t = 0; t < nt2; ++t) {
    const int k0 = t * 128;
    const bool more = (t + 1 < nt2);
    const bool need_mask = (t >= ntFull);

    if (more) {
      const int k0n = k0 + 128;
#pragma unroll
      for (int hh = 0; hh < 2; ++hh)
#pragma unroll
        for (int p = 0; p < 2; ++p) {
          const int qw = sq * 2 + p;
          kreg[hh][p] = *(const us8*)(K  + (size_t)(k0n + hh * 64 + sr) * DMODEL + h * HDIM + qw * 8);
          vreg[hh][p] = *(const us8*)(Vt + (size_t)(h * HDIM + sr) * S_LEN + k0n + hh * 64 + qw * 8);
        }
    }

    // ---- S^T = K Q^T over 128 kv (swapped operands; 16 MFMA) ----
    // lane holds: q = w*16+lr (col), kv = hh*64 + cb*16 + lg*4 + reg (row)
    f32x4 sacc[2][4] = {};
    __builtin_amdgcn_s_setprio(1);
#pragma unroll
    for (int hh = 0; hh < 2; ++hh)
#pragma unroll
      for (int kc = 0; kc < 2; ++kc)
#pragma unroll
        for (int cb = 0; cb < 4; ++cb) {
          const int kv = cb * 16 + lr;
          bf16x8 kf = *(const bf16x8*)(&Ks[hh][kv * 64 + ((kc * 32 + lg * 8) ^ ((kv & 7) * 8))]);
          sacc[hh][cb] = __builtin_amdgcn_mfma_f32_16x16x32_bf16(kf, qf[kc], sacc[hh][cb], 0, 0, 0);
        }
    __builtin_amdgcn_s_setprio(0);

    // ---- mask (lane-local) ----
    if (need_mask) {
#pragma unroll
      for (int hh = 0; hh < 2; ++hh)
#pragma unroll
        for (int cb = 0; cb < 4; ++cb)
#pragma unroll
          for (int r = 0; r < 4; ++r) {
            const int kg = k0 + hh * 64 + cb * 16 + lg * 4 + r;
            if (kg > qg) sacc[hh][cb][r] = -1e30f;
          }
    }

    // ---- row max: lane-local tree + 2 shfl ----
    float mx = -1e30f;
#pragma unroll
    for (int hh = 0; hh < 2; ++hh)
#pragma unroll
      for (int cb = 0; cb < 4; ++cb) {
        float a = fmaxf(sacc[hh][cb][0], sacc[hh][cb][1]);
        float b = fmaxf(sacc[hh][cb][2], sacc[hh][cb][3]);
        mx = fmaxf(mx, fmaxf(a, b));
      }
    mx = fmaxf(mx, __shfl_xor(mx, 16));
    mx = fmaxf(mx, __shfl_xor(mx, 32));

    // ---- defer-max ----
    const int ok = (mx <= m_i + 8.f);
    if (!__all(ok)) {
      const float mnew = fmaxf(m_i, mx);
      const float alpha = __builtin_amdgcn_exp2f(m_i - mnew);
      m_i = mnew;
      l_i *= alpha;
      float ar[4];
#pragma unroll
      for (int r = 0; r < 4; ++r) ar[r] = __shfl(alpha, lg * 4 + r);
#pragma unroll
      for (int db = 0; db < 4; ++db)
#pragma unroll
        for (int r = 0; r < 4; ++r) o_acc[db][r] *= ar[r];
    }

    // ---- exp2 + rowsum (lane-local) ----
    float p[8][4];
    float rs = 0.f;
#pragma unroll
    for (int hh = 0; hh < 2; ++hh)
#pragma unroll
      for (int cb = 0; cb < 4; ++cb)
#pragma unroll
        for (int r = 0; r < 4; ++r) {
          const float e = __builtin_amdgcn_exp2f(sacc[hh][cb][r] - m_i);
          p[hh * 4 + cb][r] = e;
          rs += e;
        }
    rs += __shfl_xor(rs, 16);
    rs += __shfl_xor(rs, 32);
    l_i += rs;

    // ---- pack to bf16 pairs: pk[b][w] = (kv = b*16 + lg*4 + 2w, +1) ----
    unsigned int pk[8][2];
#pragma unroll
    for (int b = 0; b < 8; ++b) {
      pk[b][0] = cvt_pk(p[b][0], p[b][1]);
      pk[b][1] = cvt_pk(p[b][2], p[b][3]);
    }

    // ---- 2-stage butterfly -> PV A-frags in registers ----
    unsigned int z0[4][2], z1[4][2];
#pragma unroll
    for (int k = 0; k < 4; ++k)
#pragma unroll
      for (int v = 0; v < 2; ++v) {
        const unsigned int x0 = pk[2 * k][v];
        const unsigned int x1 = pk[2 * k + 1][v];
        const unsigned int snd = hiP ? x0 : x1;
        const unsigned int rcv = (unsigned int)__shfl_xor((int)snd, 32);
        const unsigned int y0 = hiP ? rcv : x0;
        const unsigned int y1 = hiP ? x1 : rcv;
        const unsigned int s2 = hiQ ? y0 : y1;
        const unsigned int r2 = (unsigned int)__shfl_xor((int)s2, 16);
        z0[k][v] = hiQ ? r2 : y0;
        z1[k][v] = hiQ ? y1 : r2;
      }

    // ---- O += P V over 128 kv (16 MFMA; A from registers) ----
    __builtin_amdgcn_s_setprio(1);
#pragma unroll
    for (int kc2 = 0; kc2 < 4; ++kc2) {
      union { unsigned int u[4]; bf16x8 v; } pa;
      pa.u[0] = z0[kc2][0]; pa.u[1] = z0[kc2][1];
      pa.u[2] = z1[kc2][0]; pa.u[3] = z1[kc2][1];
      const int hh = kc2 >> 1, kc = kc2 & 1;
#pragma unroll
      for (int db = 0; db < 4; ++db) {
        const int d = db * 16 + lr;
        bf16x8 vf = *(const bf16x8*)(&Vs[hh][d * 64 + ((kc * 32 + lg * 8) ^ ((d & 7) * 8))]);
        o_acc[db] = __builtin_amdgcn_mfma_f32_16x16x32_bf16(pa.v, vf, o_acc[db], 0, 0, 0);
      }
    }
    __builtin_amdgcn_s_setprio(0);

    __syncthreads();
    if (more) {
#pragma unroll
      for (int hh = 0; hh < 2; ++hh)
#pragma unroll
        for (int p2 = 0; p2 < 2; ++p2) {
          const int qw = sq * 2 + p2;
          const int sw = (qw * 8) ^ ((sr & 7) * 8);
          *(us8*)(&Ks[hh][sr * 64 + sw]) = kreg[hh][p2];
          *(us8*)(&Vs[hh][sr * 64 + sw]) = vreg[hh][p2];
        }
      __syncthreads();
    }
  }

  // ---- epilogue: fetch row l via shfl, normalize, store ----
  float lrow[4];
#pragma unroll
  for (int r = 0; r < 4; ++r) lrow[r] = __shfl(l_i, lg * 4 + r);
#pragma unroll
  for (int r = 0; r < 4; ++r) {
    const float inv = 1.f / lrow[r];
    const int row = q0 + w * 16 + lg * 4 + r;
#pragma unroll
    for (int db = 0; db < 4; ++db)
      O[(size_t)row * DMODEL + h * HDIM + db * 16 + lr] = f2b_fast(o_acc[db][r] * inv);
  }
}

// ---------------------------------------------------------------------------
extern "C" void kernel_launch(void* const* d_in, const int* in_sizes, int n_in,
                              void* d_out, int out_size, void* d_ws, size_t ws_size,
                              hipStream_t stream) {
  const float* x  = (const float*)d_in[0];
  const float* Wq = (const float*)d_in[1];
  const float* Wk = (const float*)d_in[2];
  const float* Wv = (const float*)d_in[3];
  const float* Wo = (const float*)d_in[4];
  const float* bo = (const float*)d_in[5];
  float* out = (float*)d_out;

  const size_t SD = (size_t)S_LEN * DMODEL;   // 3,145,728
  const size_t DD = (size_t)DMODEL * DMODEL;  //   589,824

  unsigned short* xh   = (unsigned short*)d_ws;
  unsigned short* Wqh  = xh   + SD;
  unsigned short* Wkh  = Wqh  + DD;
  unsigned short* Wvh  = Wkh  + DD;
  unsigned short* Woh  = Wvh  + DD;
  unsigned short* Qh   = Woh  + DD;
  unsigned short* Kh   = Qh   + SD;
  unsigned short* Vh   = Kh   + SD;
  unsigned short* Vth  = Vh   + SD;
  unsigned short* ctxh = Vth  + SD;

  const dim3 blk(256);

  cvt_f2b_kern<<<dim3((int)(SD / 8 / 256)), blk, 0, stream>>>(x, xh, (int)SD);
  cvt_f2b4_kern<<<dim3((int)(DD / 8 / 256), 4), blk, 0, stream>>>(
      Wq, Wk, Wv, Wo, Wqh, Wkh, Wvh, Woh, (int)DD);

  gemm_qkv_lds<<<dim3(DMODEL / 64, S_LEN / 64, 3), blk, 0, stream>>>(
      xh, Wqh, Wkh, Wvh, Qh, Kh, Vh);

  transpose_bf16<<<dim3(DMODEL / 64, S_LEN / 64), blk, 0, stream>>>(Vh, Vth);

  attn_fwd_mfma<<<dim3(S_LEN / 64 * NHEAD), blk, 0, stream>>>(Qh, Kh, Vth, ctxh);

  gemm_lds_f32<<<dim3(DMODEL / 64, S_LEN / 64), blk, 0, stream>>>(ctxh, Woh, bo, out);
}

// Round 37
// 128.816 us; speedup vs baseline: 1.3714x; 1.3714x over previous
//
#include <hip/hip_runtime.h>
#include <math.h>

static constexpr int S_LEN  = 4096;
static constexpr int DMODEL = 768;
static constexpr int NHEAD  = 12;
static constexpr int HDIM   = 64;

typedef __attribute__((ext_vector_type(8))) short   bf16x8;
typedef __attribute__((ext_vector_type(4))) float   f32x4;
typedef __attribute__((ext_vector_type(8))) unsigned short us8;

__device__ __forceinline__ unsigned short f2b(float f) {
  union { float f; unsigned int u; } v; v.f = f;
  unsigned int u = v.u;
  return (unsigned short)((u + 0x7fffu + ((u >> 16) & 1u)) >> 16);  // RNE
}

// HW bf16 convert (RNE)
__device__ __forceinline__ unsigned short f2b_fast(float f) {
  unsigned int u;
  asm("v_cvt_pk_bf16_f32 %0, %1, %2" : "=v"(u) : "v"(f), "v"(0.f));
  return (unsigned short)u;
}
__device__ __forceinline__ unsigned int cvt_pk(float lo, float hi) {
  unsigned int u;
  asm("v_cvt_pk_bf16_f32 %0, %1, %2" : "=v"(u) : "v"(lo), "v"(hi));
  return u;
}

// ---------------------------------------------------------------------------
// fp32 -> bf16 bulk convert
// ---------------------------------------------------------------------------
__global__ __launch_bounds__(256)
void cvt_f2b_kern(const float* __restrict__ in, unsigned short* __restrict__ out, int n) {
  int i = (blockIdx.x * blockDim.x + threadIdx.x) * 8;
  if (i >= n) return;
  float4 a = *(const float4*)(in + i);
  float4 b = *(const float4*)(in + i + 4);
  ushort4 o0; o0.x = f2b(a.x); o0.y = f2b(a.y); o0.z = f2b(a.z); o0.w = f2b(a.w);
  ushort4 o1; o1.x = f2b(b.x); o1.y = f2b(b.y); o1.z = f2b(b.z); o1.w = f2b(b.w);
  *(ushort4*)(out + i)     = o0;
  *(ushort4*)(out + i + 4) = o1;
}

// 4 weight matrices in one launch (blockIdx.y selects the matrix)
__global__ __launch_bounds__(256)
void cvt_f2b4_kern(const float* __restrict__ s0, const float* __restrict__ s1,
                   const float* __restrict__ s2, const float* __restrict__ s3,
                   unsigned short* __restrict__ d0, unsigned short* __restrict__ d1,
                   unsigned short* __restrict__ d2, unsigned short* __restrict__ d3,
                   int n) {
  const float* s; unsigned short* d;
  switch (blockIdx.y) {
    case 0: s = s0; d = d0; break;
    case 1: s = s1; d = d1; break;
    case 2: s = s2; d = d2; break;
    default: s = s3; d = d3; break;
  }
  int i = (blockIdx.x * blockDim.x + threadIdx.x) * 8;
  if (i >= n) return;
  float4 a = *(const float4*)(s + i);
  float4 b = *(const float4*)(s + i + 4);
  ushort4 o0; o0.x = f2b(a.x); o0.y = f2b(a.y); o0.z = f2b(a.z); o0.w = f2b(a.w);
  ushort4 o1; o1.x = f2b(b.x); o1.y = f2b(b.y); o1.z = f2b(b.z); o1.w = f2b(b.w);
  *(ushort4*)(d + i)     = o0;
  *(ushort4*)(d + i + 4) = o1;
}

// ---------------------------------------------------------------------------
// bf16 transpose: in [S][D] -> out [D][S], 64x64 tiles via LDS.
// ---------------------------------------------------------------------------
__global__ __launch_bounds__(256)
void transpose_bf16(const unsigned short* __restrict__ in, unsigned short* __restrict__ out) {
  __shared__ __align__(16) unsigned short Ts[64][72];
  const int d0 = blockIdx.x * 64, s0 = blockIdx.y * 64;
  const int r = threadIdx.x >> 2, q = threadIdx.x & 3;
#pragma unroll
  for (int hh = 0; hh < 2; ++hh) {
    const int c8 = q + hh * 4;
    us8 v = *(const us8*)(in + (size_t)(s0 + r) * DMODEL + d0 + c8 * 8);
    *(us8*)(&Ts[r][c8 * 8]) = v;
  }
  __syncthreads();
#pragma unroll
  for (int hh = 0; hh < 2; ++hh) {
    const int sq = q + hh * 4;
    __align__(16) unsigned short tmp[8];
#pragma unroll
    for (int j = 0; j < 8; ++j) tmp[j] = Ts[sq * 8 + j][r];
    *(us8*)(out + (size_t)(d0 + r) * S_LEN + s0 + sq * 8) = *(us8*)tmp;
  }
}

// ---------------------------------------------------------------------------
// LDS-staged GEMM body (unchanged from R30/R31 measured build).
// ---------------------------------------------------------------------------
template<int OUT_MODE>
__device__ __forceinline__
void gemm_body(const unsigned short* __restrict__ A, const unsigned short* __restrict__ B,
               const float* __restrict__ bias, void* __restrict__ Cout,
               int M, int N, int K, float scale, int bx, int by,
               unsigned short* As, unsigned short* Bs) {
  const int l  = threadIdx.x & 63;
  const int w  = threadIdx.x >> 6;
  const int wm = (w >> 1) * 32, wn = (w & 1) * 32;
  const int m0 = by * 64;
  const int n0 = bx * 64;
  const int lr = l & 15, lg = l >> 4;
  const int sr = threadIdx.x >> 2, sq = threadIdx.x & 3;

  f32x4 acc[2][2] = {};
  us8 areg[2], breg[2];

#pragma unroll
  for (int p = 0; p < 2; ++p) {
    const int c = sq * 2 + p;
    areg[p] = *(const us8*)(A + (size_t)(m0 + sr) * K + c * 8);
    breg[p] = *(const us8*)(B + (size_t)(n0 + sr) * K + c * 8);
  }
#pragma unroll
  for (int p = 0; p < 2; ++p) {
    const int c = sq * 2 + p;
    const int slot = ((c ^ (sr & 7)) * 8);
    *(us8*)(&As[sr * 64 + slot]) = areg[p];
    *(us8*)(&Bs[sr * 64 + slot]) = breg[p];
  }
  __syncthreads();

  const int nsteps = K / 64;  // 12
  for (int t = 0; t < nsteps; ++t) {
    const bool more = (t + 1 < nsteps);
    if (more) {
      const int kn = (t + 1) * 64;
#pragma unroll
      for (int p = 0; p < 2; ++p) {
        const int c = sq * 2 + p;
        areg[p] = *(const us8*)(A + (size_t)(m0 + sr) * K + kn + c * 8);
        breg[p] = *(const us8*)(B + (size_t)(n0 + sr) * K + kn + c * 8);
      }
    }
#pragma unroll
    for (int kc = 0; kc < 2; ++kc) {
      const int cr = kc * 4 + lg;
      bf16x8 af[2], bfr[2];
#pragma unroll
      for (int mi = 0; mi < 2; ++mi) {
        const int row = wm + mi * 16 + lr;
        af[mi] = *(const bf16x8*)(&As[row * 64 + ((cr ^ (row & 7)) * 8)]);
      }
#pragma unroll
      for (int ni = 0; ni < 2; ++ni) {
        const int row = wn + ni * 16 + lr;
        bfr[ni] = *(const bf16x8*)(&Bs[row * 64 + ((cr ^ (row & 7)) * 8)]);
      }
#pragma unroll
      for (int mi = 0; mi < 2; ++mi)
#pragma unroll
        for (int ni = 0; ni < 2; ++ni)
          acc[mi][ni] = __builtin_amdgcn_mfma_f32_16x16x32_bf16(af[mi], bfr[ni], acc[mi][ni], 0, 0, 0);
    }
    __syncthreads();
    if (more) {
#pragma unroll
      for (int p = 0; p < 2; ++p) {
        const int c = sq * 2 + p;
        const int slot = ((c ^ (sr & 7)) * 8);
        *(us8*)(&As[sr * 64 + slot]) = areg[p];
        *(us8*)(&Bs[sr * 64 + slot]) = breg[p];
      }
      __syncthreads();
    }
  }

  const int orow = (l >> 4) * 4;
#pragma unroll
  for (int mi = 0; mi < 2; ++mi)
#pragma unroll
    for (int ni = 0; ni < 2; ++ni) {
      const int col = n0 + wn + ni * 16 + lr;
      float bb = (OUT_MODE == 1) ? bias[col] : 0.f;
#pragma unroll
      for (int r = 0; r < 4; ++r) {
        const int row = m0 + wm + mi * 16 + orow + r;
        float v = acc[mi][ni][r] * scale;
        if (OUT_MODE == 0)
          ((unsigned short*)Cout)[(size_t)row * N + col] = f2b(v);
        else
          ((float*)Cout)[(size_t)row * N + col] = v + bb;
      }
    }
}

// Fused QKV projection. Q scale = 0.125 * log2(e): softmax runs in exp2 domain.
__global__ __launch_bounds__(256)
void gemm_qkv_lds(const unsigned short* __restrict__ X,
                  const unsigned short* __restrict__ Wq, const unsigned short* __restrict__ Wk,
                  const unsigned short* __restrict__ Wv,
                  unsigned short* __restrict__ Qh, unsigned short* __restrict__ Kh,
                  unsigned short* __restrict__ Vh) {
  __shared__ __align__(16) unsigned short As[64 * 64];
  __shared__ __align__(16) unsigned short Bs[64 * 64];
  const unsigned short* B; unsigned short* C; float scale;
  switch (blockIdx.z) {
    case 0:  B = Wq; C = Qh; scale = 0.125f * 1.4426950408889634f; break;
    case 1:  B = Wk; C = Kh; scale = 1.0f;   break;
    default: B = Wv; C = Vh; scale = 1.0f;   break;
  }
  gemm_body<0>(X, B, nullptr, C, S_LEN, DMODEL, DMODEL, scale,
               blockIdx.x, blockIdx.y, As, Bs);
}

// Single GEMM (final projection, fp32 out + bias)
__global__ __launch_bounds__(256)
void gemm_lds_f32(const unsigned short* __restrict__ A, const unsigned short* __restrict__ B,
                  const float* __restrict__ bias, float* __restrict__ C) {
  __shared__ __align__(16) unsigned short As[64 * 64];
  __shared__ __align__(16) unsigned short Bs[64 * 64];
  gemm_body<1>(A, B, bias, C, S_LEN, DMODEL, DMODEL, 1.0f,
               blockIdx.x, blockIdx.y, As, Bs);
}

// ---------------------------------------------------------------------------
// Flash-style causal attention (R32 structure: swapped QK^T, lane-local
// softmax, in-register P butterfly). R37: relieve register pressure —
// launch_bounds (256,4) (VGPR cap 128 vs 102) and exp2+rowsum+pack fused
// (p[8][4] never materialized; sacc consumed in place).
// ---------------------------------------------------------------------------
__global__ __launch_bounds__(256, 4)
void attn_fwd_mfma(const unsigned short* __restrict__ Q, const unsigned short* __restrict__ K,
                   const unsigned short* __restrict__ Vt, unsigned short* __restrict__ O) {
  __shared__ __align__(16) unsigned short Ks[2][64 * 64];
  __shared__ __align__(16) unsigned short Vs[2][64 * 64];

  const int item = blockIdx.x;
  int s;
  if (item < 256)      s = item;
  else if (item < 512) s = 767 - item;
  else                 s = item;
  const int qt = 63 - s / NHEAD;
  const int h  = s % NHEAD;
  const int q0 = qt * 64;
  const int tid = threadIdx.x;
  const int w = tid >> 6, l = tid & 63;
  const int lr = l & 15, lg = l >> 4;
  const int sr = tid >> 2, sq = tid & 3;
  const bool hiP = (lg >= 2);      // lg bit1
  const bool hiQ = (lg & 1) != 0;  // lg bit0

  bf16x8 qf[2];
#pragma unroll
  for (int kc = 0; kc < 2; ++kc)
    qf[kc] = *(const bf16x8*)(Q + (size_t)(q0 + w * 16 + lr) * DMODEL + h * HDIM + kc * 32 + lg * 8);

  f32x4 o_acc[4] = {};
  float m_i = -1e30f, l_i = 0.f;
  const int qg = q0 + w * 16 + lr;   // this lane's softmax row

  const int nt2    = (qt + 2) >> 1;
  const int ntFull = (64 * qt >= 127) ? ((64 * qt - 127) / 128 + 1) : 0;

  us8 kreg[2][2], vreg[2][2];

#pragma unroll
  for (int hh = 0; hh < 2; ++hh)
#pragma unroll
    for (int p = 0; p < 2; ++p) {
      const int qw = sq * 2 + p;
      kreg[hh][p] = *(const us8*)(K  + (size_t)(hh * 64 + sr) * DMODEL + h * HDIM + qw * 8);
      vreg[hh][p] = *(const us8*)(Vt + (size_t)(h * HDIM + sr) * S_LEN + hh * 64 + qw * 8);
    }
#pragma unroll
  for (int hh = 0; hh < 2; ++hh)
#pragma unroll
    for (int p = 0; p < 2; ++p) {
      const int qw = sq * 2 + p;
      const int sw = (qw * 8) ^ ((sr & 7) * 8);
      *(us8*)(&Ks[hh][sr * 64 + sw]) = kreg[hh][p];
      *(us8*)(&Vs[hh][sr * 64 + sw]) = vreg[hh][p];
    }
  __syncthreads();

  for (int t = 0; t < nt2; ++t) {
    const int k0 = t * 128;
    const bool more = (t + 1 < nt2);
    const bool need_mask = (t >= ntFull);

    if (more) {
      const int k0n = k0 + 128;
#pragma unroll
      for (int hh = 0; hh < 2; ++hh)
#pragma unroll
        for (int p = 0; p < 2; ++p) {
          const int qw = sq * 2 + p;
          kreg[hh][p] = *(const us8*)(K  + (size_t)(k0n + hh * 64 + sr) * DMODEL + h * HDIM + qw * 8);
          vreg[hh][p] = *(const us8*)(Vt + (size_t)(h * HDIM + sr) * S_LEN + k0n + hh * 64 + qw * 8);
        }
    }

    // ---- S^T = K Q^T over 128 kv (swapped operands; 16 MFMA) ----
    f32x4 sacc[2][4] = {};
    __builtin_amdgcn_s_setprio(1);
#pragma unroll
    for (int hh = 0; hh < 2; ++hh)
#pragma unroll
      for (int kc = 0; kc < 2; ++kc)
#pragma unroll
        for (int cb = 0; cb < 4; ++cb) {
          const int kv = cb * 16 + lr;
          bf16x8 kf = *(const bf16x8*)(&Ks[hh][kv * 64 + ((kc * 32 + lg * 8) ^ ((kv & 7) * 8))]);
          sacc[hh][cb] = __builtin_amdgcn_mfma_f32_16x16x32_bf16(kf, qf[kc], sacc[hh][cb], 0, 0, 0);
        }
    __builtin_amdgcn_s_setprio(0);

    // ---- mask (lane-local) ----
    if (need_mask) {
#pragma unroll
      for (int hh = 0; hh < 2; ++hh)
#pragma unroll
        for (int cb = 0; cb < 4; ++cb)
#pragma unroll
          for (int r = 0; r < 4; ++r) {
            const int kg = k0 + hh * 64 + cb * 16 + lg * 4 + r;
            if (kg > qg) sacc[hh][cb][r] = -1e30f;
          }
    }

    // ---- row max: lane-local tree + 2 shfl ----
    float mx = -1e30f;
#pragma unroll
    for (int hh = 0; hh < 2; ++hh)
#pragma unroll
      for (int cb = 0; cb < 4; ++cb) {
        float a = fmaxf(sacc[hh][cb][0], sacc[hh][cb][1]);
        float b = fmaxf(sacc[hh][cb][2], sacc[hh][cb][3]);
        mx = fmaxf(mx, fmaxf(a, b));
      }
    mx = fmaxf(mx, __shfl_xor(mx, 16));
    mx = fmaxf(mx, __shfl_xor(mx, 32));

    // ---- defer-max ----
    const int ok = (mx <= m_i + 8.f);
    if (!__all(ok)) {
      const float mnew = fmaxf(m_i, mx);
      const float alpha = __builtin_amdgcn_exp2f(m_i - mnew);
      m_i = mnew;
      l_i *= alpha;
      float ar[4];
#pragma unroll
      for (int r = 0; r < 4; ++r) ar[r] = __shfl(alpha, lg * 4 + r);
#pragma unroll
      for (int db = 0; db < 4; ++db)
#pragma unroll
        for (int r = 0; r < 4; ++r) o_acc[db][r] *= ar[r];
    }

    // ---- exp2 + rowsum + pack (fused; sacc consumed in place) ----
    unsigned int pk[8][2];
    float rs = 0.f;
#pragma unroll
    for (int b = 0; b < 8; ++b) {
      const int hh = b >> 2, cb = b & 3;
      const float e0 = __builtin_amdgcn_exp2f(sacc[hh][cb][0] - m_i);
      const float e1 = __builtin_amdgcn_exp2f(sacc[hh][cb][1] - m_i);
      const float e2 = __builtin_amdgcn_exp2f(sacc[hh][cb][2] - m_i);
      const float e3 = __builtin_amdgcn_exp2f(sacc[hh][cb][3] - m_i);
      rs += (e0 + e1) + (e2 + e3);
      pk[b][0] = cvt_pk(e0, e1);
      pk[b][1] = cvt_pk(e2, e3);
    }
    rs += __shfl_xor(rs, 16);
    rs += __shfl_xor(rs, 32);
    l_i += rs;

    // ---- 2-stage butterfly -> PV A-frags in registers ----
    unsigned int z0[4][2], z1[4][2];
#pragma unroll
    for (int k = 0; k < 4; ++k)
#pragma unroll
      for (int v = 0; v < 2; ++v) {
        const unsigned int x0 = pk[2 * k][v];
        const unsigned int x1 = pk[2 * k + 1][v];
        const unsigned int snd = hiP ? x0 : x1;
        const unsigned int rcv = (unsigned int)__shfl_xor((int)snd, 32);
        const unsigned int y0 = hiP ? rcv : x0;
        const unsigned int y1 = hiP ? x1 : rcv;
        const unsigned int s2 = hiQ ? y0 : y1;
        const unsigned int r2 = (unsigned int)__shfl_xor((int)s2, 16);
        z0[k][v] = hiQ ? r2 : y0;
        z1[k][v] = hiQ ? y1 : r2;
      }

    // ---- O += P V over 128 kv (16 MFMA; A from registers) ----
    __builtin_amdgcn_s_setprio(1);
#pragma unroll
    for (int kc2 = 0; kc2 < 4; ++kc2) {
      union { unsigned int u[4]; bf16x8 v; } pa;
      pa.u[0] = z0[kc2][0]; pa.u[1] = z0[kc2][1];
      pa.u[2] = z1[kc2][0]; pa.u[3] = z1[kc2][1];
      const int hh = kc2 >> 1, kc = kc2 & 1;
#pragma unroll
      for (int db = 0; db < 4; ++db) {
        const int d = db * 16 + lr;
        bf16x8 vf = *(const bf16x8*)(&Vs[hh][d * 64 + ((kc * 32 + lg * 8) ^ ((d & 7) * 8))]);
        o_acc[db] = __builtin_amdgcn_mfma_f32_16x16x32_bf16(pa.v, vf, o_acc[db], 0, 0, 0);
      }
    }
    __builtin_amdgcn_s_setprio(0);

    __syncthreads();
    if (more) {
#pragma unroll
      for (int hh = 0; hh < 2; ++hh)
#pragma unroll
        for (int p2 = 0; p2 < 2; ++p2) {
          const int qw = sq * 2 + p2;
          const int sw = (qw * 8) ^ ((sr & 7) * 8);
          *(us8*)(&Ks[hh][sr * 64 + sw]) = kreg[hh][p2];
          *(us8*)(&Vs[hh][sr * 64 + sw]) = vreg[hh][p2];
        }
      __syncthreads();
    }
  }

  // ---- epilogue: fetch row l via shfl, normalize, store ----
  float lrow[4];
#pragma unroll
  for (int r = 0; r < 4; ++r) lrow[r] = __shfl(l_i, lg * 4 + r);
#pragma unroll
  for (int r = 0; r < 4; ++r) {
    const float inv = 1.f / lrow[r];
    const int row = q0 + w * 16 + lg * 4 + r;
#pragma unroll
    for (int db = 0; db < 4; ++db)
      O[(size_t)row * DMODEL + h * HDIM + db * 16 + lr] = f2b_fast(o_acc[db][r] * inv);
  }
}

// ---------------------------------------------------------------------------
extern "C" void kernel_launch(void* const* d_in, const int* in_sizes, int n_in,
                              void* d_out, int out_size, void* d_ws, size_t ws_size,
                              hipStream_t stream) {
  const float* x  = (const float*)d_in[0];
  const float* Wq = (const float*)d_in[1];
  const float* Wk = (const float*)d_in[2];
  const float* Wv = (const float*)d_in[3];
  const float* Wo = (const float*)d_in[4];
  const float* bo = (const float*)d_in[5];
  float* out = (float*)d_out;

  const size_t SD = (size_t)S_LEN * DMODEL;   // 3,145,728
  const size_t DD = (size_t)DMODEL * DMODEL;  //   589,824

  unsigned short* xh   = (unsigned short*)d_ws;
  unsigned short* Wqh  = xh   + SD;
  unsigned short* Wkh  = Wqh  + DD;
  unsigned short* Wvh  = Wkh  + DD;
  unsigned short* Woh  = Wvh  + DD;
  unsigned short* Qh   = Woh  + DD;
  unsigned short* Kh   = Qh   + SD;
  unsigned short* Vh   = Kh   + SD;
  unsigned short* Vth  = Vh   + SD;
  unsigned short* ctxh = Vth  + SD;

  const dim3 blk(256);

  cvt_f2b_kern<<<dim3((int)(SD / 8 / 256)), blk, 0, stream>>>(x, xh, (int)SD);
  cvt_f2b4_kern<<<dim3((int)(DD / 8 / 256), 4), blk, 0, stream>>>(
      Wq, Wk, Wv, Wo, Wqh, Wkh, Wvh, Woh, (int)DD);

  gemm_qkv_lds<<<dim3(DMODEL / 64, S_LEN / 64, 3), blk, 0, stream>>>(
      xh, Wqh, Wkh, Wvh, Qh, Kh, Vh);

  transpose_bf16<<<dim3(DMODEL / 64, S_LEN / 64), blk, 0, stream>>>(Vh, Vth);

  attn_fwd_mfma<<<dim3(S_LEN / 64 * NHEAD), blk, 0, stream>>>(Qh, Kh, Vth, ctxh);

  gemm_lds_f32<<<dim3(DMODEL / 64, S_LEN / 64), blk, 0, stream>>>(ctxh, Woh, bo, out);
}